// Round 1
// 1523.455 us; speedup vs baseline: 1.0723x; 1.0723x over previous
//
#include <hip/hip_runtime.h>
#include <hip/hip_bf16.h>
#include <stdint.h>

#define NODES 50000
#define RELS  4
#define EDGES 1600000
#define FEAT  256
#define NCLS  16
#define MPAD  50048                 // 391 * 128
#define RPS   50016                 // row_ptr per-relation stride
#define SCHUNK 1024                 // scan elements per block
#define NSBLK  49                   // ceil(50000/1024)
#define NCHUNK 64                   // edge chunks per relation
#define CHUNKE 25000                // EDGES / NCHUNK
#define NB     782                  // node buckets of 64 rows (781*64+16)

typedef __attribute__((ext_vector_type(8))) short short8;
typedef __attribute__((ext_vector_type(8))) unsigned short u16x8;
typedef __attribute__((ext_vector_type(4))) float f32x4;

static __device__ __forceinline__ float bf2f(unsigned short u) {
    return __uint_as_float(((unsigned int)u) << 16);
}
static __device__ __forceinline__ unsigned short f2bf(float f) {
    unsigned int x = __float_as_uint(f);
    unsigned int r = x + 0x7fffu + ((x >> 16) & 1u);
    return (unsigned short)(r >> 16);
}

// ============ CSR build: bucket radix sort, zero global atomics ============

// per-(rel,chunk) LDS histogram of value>>6 -> part[rel][chunk][NB]
__global__ __launch_bounds__(256)
void k_bhist(const int* __restrict__ edges, int arr_off, unsigned* __restrict__ part) {
    int chunk = blockIdx.x, rel = blockIdx.y, t = threadIdx.x;
    const int* arr = edges + (size_t)rel * 2 * EDGES + arr_off + (size_t)chunk * CHUNKE;
    __shared__ unsigned h[NB];
    for (int i = t; i < NB; i += 256) h[i] = 0;
    __syncthreads();
    for (int e = t; e < CHUNKE; e += 256) atomicAdd(&h[((unsigned)arr[e]) >> 6], 1u);
    __syncthreads();
    unsigned* po = part + ((size_t)rel * NCHUNK + chunk) * NB;
    for (int i = t; i < NB; i += 256) po[i] = h[i];
}

// per relation: bucket bases (exclusive scan of totals) + per-(chunk,bucket) offsets
__global__ __launch_bounds__(256)
void k_bscan(const unsigned* __restrict__ part, unsigned* __restrict__ off,
             unsigned* __restrict__ bbase) {
    int rel = blockIdx.x, t = threadIdx.x;
    const int BPT = 4;                       // 256*4 >= NB
    int b0 = t * BPT;
    unsigned s = 0;
#pragma unroll
    for (int j = 0; j < BPT; ++j) {
        int b = b0 + j;
        unsigned x = 0;
        if (b < NB)
            for (int c = 0; c < NCHUNK; ++c)
                x += part[((size_t)rel * NCHUNK + c) * NB + b];
        s += x;
    }
    __shared__ unsigned sh[256];
    sh[t] = s;
    __syncthreads();
    for (int o = 1; o < 256; o <<= 1) {
        unsigned u = (t >= o) ? sh[t - o] : 0;
        __syncthreads();
        sh[t] += u;
        __syncthreads();
    }
    unsigned base = sh[t] - s;
#pragma unroll
    for (int j = 0; j < BPT; ++j) {
        int b = b0 + j;
        if (b < NB) {
            bbase[rel * (NB + 1) + b] = base;
            unsigned acc = base;
            for (int c = 0; c < NCHUNK; ++c) {
                size_t o2 = ((size_t)rel * NCHUNK + c) * NB + b;
                off[o2] = acc;
                acc += part[o2];
            }
            base = acc;
        }
    }
    if (t == 255) bbase[rel * (NB + 1) + NB] = sh[255];
}

// scatter (row,col) pairs into row-bucket order (LDS cursors, sequential-ish writes)
__global__ __launch_bounds__(256)
void k_scatR(const int* __restrict__ edges, const unsigned* __restrict__ off,
             int2* __restrict__ ebuf) {
    int chunk = blockIdx.x, rel = blockIdx.y, t = threadIdx.x;
    const int* rows = edges + (size_t)rel * 2 * EDGES + (size_t)chunk * CHUNKE;
    const int* cols = rows + EDGES;
    __shared__ unsigned cur[NB];
    const unsigned* po = off + ((size_t)rel * NCHUNK + chunk) * NB;
    for (int i = t; i < NB; i += 256) cur[i] = po[i];
    __syncthreads();
    int2* eb = ebuf + (size_t)rel * EDGES;
    for (int e = t; e < CHUNKE; e += 256) {
        int r = rows[e], c = cols[e];
        unsigned pos = atomicAdd(&cur[((unsigned)r) >> 6], 1u);
        eb[pos] = make_int2(r, c);
    }
}

// scatter col values into col-bucket order (for col-degree counting)
__global__ __launch_bounds__(256)
void k_scatC(const int* __restrict__ edges, const unsigned* __restrict__ off,
             int* __restrict__ cbuf) {
    int chunk = blockIdx.x, rel = blockIdx.y, t = threadIdx.x;
    const int* cols = edges + (size_t)rel * 2 * EDGES + EDGES + (size_t)chunk * CHUNKE;
    __shared__ unsigned cur[NB];
    const unsigned* po = off + ((size_t)rel * NCHUNK + chunk) * NB;
    for (int i = t; i < NB; i += 256) cur[i] = po[i];
    __syncthreads();
    int* cb = cbuf + (size_t)rel * EDGES;
    for (int e = t; e < CHUNKE; e += 256) {
        int c = cols[e];
        unsigned pos = atomicAdd(&cur[((unsigned)c) >> 6], 1u);
        cb[pos] = c;
    }
}

// per-bucket row counts -> deg_row
__global__ __launch_bounds__(256)
void k_countR(const int2* __restrict__ ebuf, const unsigned* __restrict__ bbase,
              int* __restrict__ deg_row) {
    int b = blockIdx.x, rel = blockIdx.y, t = threadIdx.x;
    unsigned s = bbase[rel * (NB + 1) + b], e = bbase[rel * (NB + 1) + b + 1];
    __shared__ unsigned cnt[64];
    if (t < 64) cnt[t] = 0;
    __syncthreads();
    const int2* eb = ebuf + (size_t)rel * EDGES;
    for (unsigned i = s + t; i < e; i += 256) atomicAdd(&cnt[eb[i].x & 63], 1u);
    __syncthreads();
    int base = b * 64;
    if (t < 64 && base + t < NODES) deg_row[(size_t)rel * NODES + base + t] = (int)cnt[t];
}

// per-bucket col counts -> deg_col
__global__ __launch_bounds__(256)
void k_countC(const int* __restrict__ cbuf, const unsigned* __restrict__ bbase,
              int* __restrict__ deg_col) {
    int b = blockIdx.x, rel = blockIdx.y, t = threadIdx.x;
    unsigned s = bbase[rel * (NB + 1) + b], e = bbase[rel * (NB + 1) + b + 1];
    __shared__ unsigned cnt[64];
    if (t < 64) cnt[t] = 0;
    __syncthreads();
    const int* cb = cbuf + (size_t)rel * EDGES;
    for (unsigned i = s + t; i < e; i += 256) atomicAdd(&cnt[cb[i] & 63], 1u);
    __syncthreads();
    int base = b * 64;
    if (t < 64 && base + t < NODES) deg_col[(size_t)rel * NODES + base + t] = (int)cnt[t];
}

__global__ void k_dinv(const int* __restrict__ deg_row, const int* __restrict__ deg_col,
                       float* dinv_row, float* dinv_col) {
    int idx = blockIdx.x * blockDim.x + threadIdx.x;
    if (idx >= RELS * NODES) return;
    int dr = deg_row[idx]; if (dr < 1) dr = 1;
    int dc = deg_col[idx]; if (dc < 1) dc = 1;
    dinv_row[idx] = rsqrtf((float)dr);
    dinv_col[idx] = rsqrtf((float)dc);
}

// -------- parallel exclusive scan of deg_row -> row_ptr --------
__global__ __launch_bounds__(256)
void k_scanA(const int* __restrict__ deg, int* __restrict__ tmp, int* __restrict__ btot) {
    int r = blockIdx.y, blk = blockIdx.x, t = threadIdx.x;
    int i0 = blk * SCHUNK + t * 4;
    const int* d = deg + (size_t)r * NODES;
    int4 v = make_int4(0, 0, 0, 0);
    if (i0 + 3 < NODES) v = *(const int4*)(d + i0);
    else if (i0 < NODES) {
        v.x = d[i0];
        if (i0 + 1 < NODES) v.y = d[i0 + 1];
        if (i0 + 2 < NODES) v.z = d[i0 + 2];
    }
    int s = v.x + v.y + v.z + v.w;
    __shared__ int sh[256];
    sh[t] = s;
    __syncthreads();
    for (int off = 1; off < 256; off <<= 1) {
        int u = (t >= off) ? sh[t - off] : 0;
        __syncthreads();
        sh[t] += u;
        __syncthreads();
    }
    int excl = sh[t] - s;
    int4 o;
    o.x = excl; o.y = excl + v.x; o.z = o.y + v.y; o.w = o.z + v.z;
    int* tp = tmp + (size_t)r * NODES;
    if (i0 + 3 < NODES) *(int4*)(tp + i0) = o;
    else if (i0 < NODES) {
        tp[i0] = o.x;
        if (i0 + 1 < NODES) tp[i0 + 1] = o.y;
        if (i0 + 2 < NODES) tp[i0 + 2] = o.z;
    }
    if (t == 255) btot[r * 64 + blk] = sh[255];
}

__global__ void k_scanB(int* __restrict__ btot, int* __restrict__ row_ptr) {
    int r = blockIdx.x;
    if (threadIdx.x != 0) return;
    int acc = 0;
    for (int b = 0; b < NSBLK; ++b) {
        int v = btot[r * 64 + b];
        btot[r * 64 + b] = acc;
        acc += v;
    }
    row_ptr[r * RPS + NODES] = acc;
}

__global__ __launch_bounds__(256)
void k_scanC(const int* __restrict__ tmp, const int* __restrict__ btot,
             int* __restrict__ row_ptr) {
    int r = blockIdx.y, blk = blockIdx.x, t = threadIdx.x;
    int i0 = blk * SCHUNK + t * 4;
    int off = btot[r * 64 + blk];
    const int* tp = tmp + (size_t)r * NODES;
    int* rp = row_ptr + (size_t)r * RPS;
    if (i0 + 3 < NODES) {
        int4 v = *(const int4*)(tp + i0);
        rp[i0] = v.x + off; rp[i0 + 1] = v.y + off;
        rp[i0 + 2] = v.z + off; rp[i0 + 3] = v.w + off;
    } else if (i0 < NODES) {
        for (int j = 0; j < 4 && i0 + j < NODES; ++j)
            rp[i0 + j] = tp[i0 + j] + off;
    }
}

// per-bucket exact CSR fill: 64 LDS cursors, bucket csr range is contiguous (~8 KB)
__global__ __launch_bounds__(256)
void k_place(const int2* __restrict__ ebuf, const unsigned* __restrict__ bbase,
             const int* __restrict__ row_ptr, int* __restrict__ csr_col) {
    int b = blockIdx.x, rel = blockIdx.y, t = threadIdx.x;
    unsigned s = bbase[rel * (NB + 1) + b], e = bbase[rel * (NB + 1) + b + 1];
    __shared__ int cur[64];
    int base = b * 64;
    const int* rp = row_ptr + (size_t)rel * RPS;
    if (t < 64) cur[t] = (base + t < NODES) ? rp[base + t] : 0;
    __syncthreads();
    const int2* eb = ebuf + (size_t)rel * EDGES;
    int* cc = csr_col + (size_t)rel * EDGES;
    for (unsigned i = s + t; i < e; i += 256) {
        int2 ec = eb[i];
        int pos = atomicAdd(&cur[ec.x - base], 1);
        cc[pos] = ec.y;
    }
}

// ---------------- conversions ----------------

__global__ void k_f2bf(const float* __restrict__ src, unsigned short* __restrict__ dst, int count) {
    int i = blockIdx.x * blockDim.x + threadIdx.x;
    if (i < count) dst[i] = f2bf(src[i]);
}

__global__ void k_wt(const float* __restrict__ W, unsigned short* __restrict__ Wt) {
    int idx = blockIdx.x * blockDim.x + threadIdx.x;
    if (idx >= RELS * FEAT * FEAT) return;
    int r = idx >> 16;
    int rem = idx & 65535;
    int n = rem >> 8;
    int k = rem & 255;
    Wt[idx] = f2bf(W[(size_t)r * FEAT * FEAT + (size_t)k * FEAT + n]);
}

// ---------------- SPMM: wave per row, 2 edges/iter, 2x unrolled, bf16 out ----------------

__global__ __launch_bounds__(256)
void k_spmm(const unsigned short* __restrict__ feat, const int* __restrict__ row_ptr,
            const int* __restrict__ csr_col, const float* __restrict__ dinv_row,
            const float* __restrict__ dinv_col, unsigned short* __restrict__ aggbf, int rel) {
    int wave = (blockIdx.x * blockDim.x + threadIdx.x) >> 6;
    int lane = threadIdx.x & 63;
    if (wave >= NODES) return;
    int row = wave;
    int half = lane >> 5;
    int l32  = lane & 31;
    int start = row_ptr[rel * RPS + row];
    int end   = row_ptr[rel * RPS + row + 1];
    const int* cols = csr_col + (size_t)rel * EDGES;
    const float* dc = dinv_col + rel * NODES;
    const unsigned short* fb = feat + l32 * 8;
    float acc[8] = {0.f, 0.f, 0.f, 0.f, 0.f, 0.f, 0.f, 0.f};
    int j = start + half;
    for (; j + 2 < end; j += 4) {
        int c0 = cols[j];
        int c1 = cols[j + 2];
        float w0 = dc[c0];
        float w1 = dc[c1];
        u16x8 u0 = *(const u16x8*)(fb + (size_t)c0 * FEAT);
        u16x8 u1 = *(const u16x8*)(fb + (size_t)c1 * FEAT);
#pragma unroll
        for (int i = 0; i < 8; ++i) acc[i] += w0 * bf2f(u0[i]);
#pragma unroll
        for (int i = 0; i < 8; ++i) acc[i] += w1 * bf2f(u1[i]);
    }
    if (j < end) {
        int c0 = cols[j];
        float w0 = dc[c0];
        u16x8 u0 = *(const u16x8*)(fb + (size_t)c0 * FEAT);
#pragma unroll
        for (int i = 0; i < 8; ++i) acc[i] += w0 * bf2f(u0[i]);
    }
#pragma unroll
    for (int i = 0; i < 8; ++i) acc[i] += __shfl_down(acc[i], 32, 64);
    if (half == 0) {
        float dr = dinv_row[rel * NODES + row];
        u16x8 o;
#pragma unroll
        for (int i = 0; i < 8; ++i) o[i] = f2bf(acc[i] * dr);
        *(u16x8*)(aggbf + (size_t)row * FEAT + l32 * 8) = o;
    }
}

// ---------------- MFMA GEMM (128x128 tile, BK=64, XOR-swizzled LDS) ----------------
// C/D layout: col = lane&15, row = quad*4 + reg.

__global__ __launch_bounds__(256)
void k_gemm1(const unsigned short* __restrict__ Abase, const unsigned short* __restrict__ Wt,
             unsigned short* __restrict__ h1bf) {
    __shared__ __align__(16) unsigned short As[128 * 64];
    __shared__ __align__(16) unsigned short Bs[128 * 64];
    int tid = threadIdx.x;
    int wave = tid >> 6, lane = tid & 63;
    int quad = lane >> 4, l16 = lane & 15;
    int wm = (wave & 1) * 64, wn = (wave >> 1) * 64;
    int row0 = blockIdx.x * 128, n0 = blockIdx.y * 128;

    f32x4 hacc[4][4];
#pragma unroll
    for (int mi = 0; mi < 4; ++mi)
#pragma unroll
        for (int ni = 0; ni < 4; ++ni)
            hacc[mi][ni] = (f32x4){0.f, 0.f, 0.f, 0.f};

    for (int r = 0; r < RELS; ++r) {
        const unsigned short* A  = Abase + (size_t)r * MPAD * FEAT;
        const unsigned short* Bt = Wt + (size_t)r * FEAT * FEAT;
        f32x4 acc[4][4];
#pragma unroll
        for (int mi = 0; mi < 4; ++mi)
#pragma unroll
            for (int ni = 0; ni < 4; ++ni)
                acc[mi][ni] = (f32x4){0.f, 0.f, 0.f, 0.f};

        for (int k0 = 0; k0 < FEAT; k0 += 64) {
#pragma unroll
            for (int issue = 0; issue < 4; ++issue) {
                int flat = issue * 256 + tid;
                int row = flat >> 3;
                int gr = flat & 7;
                int sg = gr ^ (row & 7);
                *(uint4*)&As[flat * 8] = *(const uint4*)(A + (size_t)(row0 + row) * FEAT + k0 + sg * 8);
                *(uint4*)&Bs[flat * 8] = *(const uint4*)(Bt + (size_t)(n0 + row) * FEAT + k0 + sg * 8);
            }
            __syncthreads();
#pragma unroll
            for (int ks = 0; ks < 2; ++ks) {
                int g = ks * 4 + quad;
                short8 af[4], bfr[4];
#pragma unroll
                for (int mi = 0; mi < 4; ++mi) {
                    int m = wm + mi * 16 + l16;
                    af[mi] = *(const short8*)&As[m * 64 + ((g ^ (m & 7)) << 3)];
                }
#pragma unroll
                for (int ni = 0; ni < 4; ++ni) {
                    int n = wn + ni * 16 + l16;
                    bfr[ni] = *(const short8*)&Bs[n * 64 + ((g ^ (n & 7)) << 3)];
                }
#pragma unroll
                for (int mi = 0; mi < 4; ++mi)
#pragma unroll
                    for (int ni = 0; ni < 4; ++ni)
                        acc[mi][ni] = __builtin_amdgcn_mfma_f32_16x16x32_bf16(af[mi], bfr[ni], acc[mi][ni], 0, 0, 0);
            }
            __syncthreads();
        }
#pragma unroll
        for (int mi = 0; mi < 4; ++mi)
#pragma unroll
            for (int ni = 0; ni < 4; ++ni)
#pragma unroll
                for (int i = 0; i < 4; ++i) {
                    float v = acc[mi][ni][i];
                    hacc[mi][ni][i] += 0.25f * (v > 0.f ? v : 0.f);
                }
    }

#pragma unroll
    for (int mi = 0; mi < 4; ++mi)
#pragma unroll
        for (int ni = 0; ni < 4; ++ni) {
            int col = n0 + wn + ni * 16 + l16;
#pragma unroll
            for (int i = 0; i < 4; ++i) {
                int row = row0 + wm + mi * 16 + quad * 4 + i;
                if (row < NODES) h1bf[(size_t)row * FEAT + col] = f2bf(hacc[mi][ni][i]);
            }
        }
}

__global__ __launch_bounds__(256)
void k_gemm2(const unsigned short* __restrict__ A, const unsigned short* __restrict__ Bt,
             unsigned short* __restrict__ H2) {
    __shared__ __align__(16) unsigned short As[128 * 64];
    __shared__ __align__(16) unsigned short Bs[128 * 64];
    int tid = threadIdx.x;
    int wave = tid >> 6, lane = tid & 63;
    int quad = lane >> 4, l16 = lane & 15;
    int wm = (wave & 1) * 64, wn = (wave >> 1) * 64;
    int row0 = blockIdx.x * 128, n0 = blockIdx.y * 128;

    f32x4 acc[4][4];
#pragma unroll
    for (int mi = 0; mi < 4; ++mi)
#pragma unroll
        for (int ni = 0; ni < 4; ++ni)
            acc[mi][ni] = (f32x4){0.f, 0.f, 0.f, 0.f};

    for (int k0 = 0; k0 < FEAT; k0 += 64) {
#pragma unroll
        for (int issue = 0; issue < 4; ++issue) {
            int flat = issue * 256 + tid;
            int row = flat >> 3;
            int gr = flat & 7;
            int sg = gr ^ (row & 7);
            *(uint4*)&As[flat * 8] = *(const uint4*)(A + (size_t)(row0 + row) * FEAT + k0 + sg * 8);
            *(uint4*)&Bs[flat * 8] = *(const uint4*)(Bt + (size_t)(n0 + row) * FEAT + k0 + sg * 8);
        }
        __syncthreads();
#pragma unroll
        for (int ks = 0; ks < 2; ++ks) {
            int g = ks * 4 + quad;
            short8 af[4], bfr[4];
#pragma unroll
            for (int mi = 0; mi < 4; ++mi) {
                int m = wm + mi * 16 + l16;
                af[mi] = *(const short8*)&As[m * 64 + ((g ^ (m & 7)) << 3)];
            }
#pragma unroll
            for (int ni = 0; ni < 4; ++ni) {
                int n = wn + ni * 16 + l16;
                bfr[ni] = *(const short8*)&Bs[n * 64 + ((g ^ (n & 7)) << 3)];
            }
#pragma unroll
            for (int mi = 0; mi < 4; ++mi)
#pragma unroll
                for (int ni = 0; ni < 4; ++ni)
                    acc[mi][ni] = __builtin_amdgcn_mfma_f32_16x16x32_bf16(af[mi], bfr[ni], acc[mi][ni], 0, 0, 0);
        }
        __syncthreads();
    }

#pragma unroll
    for (int mi = 0; mi < 4; ++mi)
#pragma unroll
        for (int ni = 0; ni < 4; ++ni) {
            int col = n0 + wn + ni * 16 + l16;
#pragma unroll
            for (int i = 0; i < 4; ++i) {
                int row = row0 + wm + mi * 16 + quad * 4 + i;
                if (row < NODES) {
                    float v = acc[mi][ni][i];
                    H2[(size_t)row * FEAT + col] = f2bf(v > 0.f ? v : 0.f);
                }
            }
        }
}

// ---------------- fused attention scores + softmax + combine + output GEMV ----------------
// One wave per node (grid-stride). Single pass over H2bf.
//  - lane l loads ushort4 of H2[r][n] at h-offset l*4 for each relation
//  - scores via in-register dot + 6-step shfl_xor butterfly (all lanes get s[r])
//  - softmax computed redundantly in all lanes; lane0 writes alpha
//  - h2 combined in registers; per-lane class partials use W_out rows 4l..4l+3
//    hoisted into registers ONCE per wave (reused across the node loop)
//  - class reduction: stride-17-padded LDS transpose (2-way bank alias = free)
//    + 2 shfl_xor; lanes 0..15 write logits

__global__ __launch_bounds__(256)
void k_attn_out(const unsigned short* __restrict__ H2bf, const float* __restrict__ att_q,
                const float* __restrict__ tau_p, const float* __restrict__ W_out,
                const float* __restrict__ b_out, float* __restrict__ alpha_out,
                float* __restrict__ logits) {
    __shared__ float red[4][64 * 17];
    int tid = threadIdx.x;
    int wid = tid >> 6;
    int lane = tid & 63;
    int gwave = blockIdx.x * 4 + wid;
    int nwaves = gridDim.x * 4;

    float4 q = *(const float4*)(att_q + lane * 4);
    float tau = fminf(fmaxf(tau_p[0], 0.5f), 5.0f);
    float itau = 1.0f / tau;
    // W_out rows 4l..4l+3 (16 classes each) -> 16 float4 in registers, loaded once
    f32x4 Wr[4][4];
#pragma unroll
    for (int j = 0; j < 4; ++j)
#pragma unroll
        for (int c4 = 0; c4 < 4; ++c4) {
            float4 w = *(const float4*)(W_out + (size_t)(lane * 4 + j) * NCLS + c4 * 4);
            Wr[j][c4] = (f32x4){w.x, w.y, w.z, w.w};
        }
    float bc = b_out[lane & 15];
    float* myred = &red[wid][0];
    int cls = lane & 15;
    int rb = (lane >> 4) * 16;

    int n = gwave;
    if (n >= NODES) return;
    ushort4 u[RELS];
#pragma unroll
    for (int r = 0; r < RELS; ++r)
        u[r] = *(const ushort4*)(H2bf + ((size_t)r * NODES + n) * FEAT + lane * 4);

    while (n < NODES) {
        int nn = n + nwaves;
        int nc = (nn < NODES) ? nn : n;   // clamp: tail re-reads current (cached, unused)
        ushort4 un[RELS];
#pragma unroll
        for (int r = 0; r < RELS; ++r)
            un[r] = *(const ushort4*)(H2bf + ((size_t)r * NODES + nc) * FEAT + lane * 4);

        float h[RELS][4];
#pragma unroll
        for (int r = 0; r < RELS; ++r) {
            h[r][0] = bf2f(u[r].x); h[r][1] = bf2f(u[r].y);
            h[r][2] = bf2f(u[r].z); h[r][3] = bf2f(u[r].w);
        }
        // scores: per-lane 4-wide dot, butterfly so ALL lanes hold full sums
        float s[RELS];
#pragma unroll
        for (int r = 0; r < RELS; ++r)
            s[r] = h[r][0] * q.x + h[r][1] * q.y + h[r][2] * q.z + h[r][3] * q.w;
#pragma unroll
        for (int off = 1; off < 64; off <<= 1) {
#pragma unroll
            for (int r = 0; r < RELS; ++r) s[r] += __shfl_xor(s[r], off, 64);
        }
        // softmax (redundant in all lanes, cheap)
        float m = fmaxf(fmaxf(s[0], s[1]), fmaxf(s[2], s[3]));
        float e[RELS];
        float esum = 0.f;
#pragma unroll
        for (int r = 0; r < RELS; ++r) { e[r] = expf((s[r] - m) * itau); esum += e[r]; }
        float inv = 1.0f / esum;
        float a[RELS];
#pragma unroll
        for (int r = 0; r < RELS; ++r) a[r] = e[r] * inv;
        if (lane == 0)
            *(float4*)(alpha_out + (size_t)n * 4) = make_float4(a[0], a[1], a[2], a[3]);

        // combine: h2 = sum_r (0.25 + alpha_r) * H2[r]
        float w0 = 0.25f + a[0], w1 = 0.25f + a[1], w2 = 0.25f + a[2], w3 = 0.25f + a[3];
        float h2[4];
#pragma unroll
        for (int j = 0; j < 4; ++j)
            h2[j] = w0 * h[0][j] + w1 * h[1][j] + w2 * h[2][j] + w3 * h[3][j];

        // per-lane partials for all 16 classes from this lane's 4 h-values
        f32x4 acc[4];
#pragma unroll
        for (int c4 = 0; c4 < 4; ++c4)
            acc[c4] = h2[0] * Wr[0][c4] + h2[1] * Wr[1][c4]
                    + h2[2] * Wr[2][c4] + h2[3] * Wr[3][c4];

        // LDS transpose-reduce: row=lane (stride 17 floats -> 2-way alias, free)
#pragma unroll
        for (int c4 = 0; c4 < 4; ++c4)
#pragma unroll
            for (int i = 0; i < 4; ++i)
                myred[lane * 17 + c4 * 4 + i] = acc[c4][i];
        asm volatile("s_waitcnt lgkmcnt(0)" ::: "memory");
        float t = 0.f;
#pragma unroll
        for (int k = 0; k < 16; ++k) t += myred[(rb + k) * 17 + cls];
        t += __shfl_xor(t, 16, 64);
        t += __shfl_xor(t, 32, 64);
        if (lane < 16) logits[(size_t)n * NCLS + lane] = t + bc;
        asm volatile("" ::: "memory");   // keep next iter's LDS writes below these reads

#pragma unroll
        for (int r = 0; r < RELS; ++r) u[r] = un[r];
        n = nn;
    }
}

// ---------------- launcher ----------------

static inline int cdiv(int a, int b) { return (a + b - 1) / b; }

extern "C" void kernel_launch(void* const* d_in, const int* in_sizes, int n_in,
                              void* d_out, int out_size, void* d_ws, size_t ws_size,
                              hipStream_t stream) {
    const float* X     = (const float*)d_in[0];
    const int*   edges = (const int*)d_in[1];
    const float* W1    = (const float*)d_in[2];
    const float* W2    = (const float*)d_in[3];
    const float* att_q = (const float*)d_in[4];
    const float* tau   = (const float*)d_in[5];
    const float* W_out = (const float*)d_in[6];
    const float* b_out = (const float*)d_in[7];

    float* logits = (float*)d_out;
    float* alpha  = logits + (size_t)NODES * NCLS;

    char* p = (char*)d_ws;
    auto carve = [&](size_t bytes) -> char* {
        char* q = p;
        p += (bytes + 255) & ~(size_t)255;
        return q;
    };
    int*   deg_row  = (int*)carve((size_t)RELS * NODES * 4);
    int*   deg_col  = (int*)carve((size_t)RELS * NODES * 4);
    float* dinv_row = (float*)carve((size_t)RELS * NODES * 4);
    float* dinv_col = (float*)carve((size_t)RELS * NODES * 4);
    int*   row_ptr  = (int*)carve((size_t)RELS * RPS * 4 + 256);
    int*   tmp      = (int*)carve((size_t)RELS * NODES * 4);
    int*   btot     = (int*)carve((size_t)RELS * 64 * 4);
    int*   csr_col  = (int*)carve((size_t)RELS * EDGES * 4);
    unsigned short* Xbf  = (unsigned short*)carve((size_t)NODES * FEAT * 2);
    unsigned short* h1bf = (unsigned short*)carve((size_t)NODES * FEAT * 2);
    unsigned short* W1t  = (unsigned short*)carve((size_t)RELS * FEAT * FEAT * 2);
    unsigned short* W2t  = (unsigned short*)carve((size_t)RELS * FEAT * FEAT * 2);
    // BIG region, phase-aliased:
    //   CSR phase:  ebuf(51.2M) | cbuf(25.6M) | partR/offR/partC/offC(~3.2M) | bbR/bbC
    //   layer 1:    agg[r] = BIG + r*AGGS (4 slices)
    //   layer 2:    agg0 = BIG, H2bf = BIG + AGGS
    const size_t AGGS = (size_t)MPAD * FEAT * 2;
    char* BIG = carve(AGGS + (size_t)RELS * NODES * FEAT * 2);
    int2*     ebuf = (int2*)BIG;
    int*      cbuf = (int*)(BIG + (size_t)RELS * EDGES * 8);
    char*     q = BIG + (size_t)RELS * EDGES * 12;
    unsigned* partR = (unsigned*)q;               q += (size_t)RELS * NCHUNK * NB * 4;
    unsigned* offR  = (unsigned*)q;               q += (size_t)RELS * NCHUNK * NB * 4;
    unsigned* partC = (unsigned*)q;               q += (size_t)RELS * NCHUNK * NB * 4;
    unsigned* offC  = (unsigned*)q;               q += (size_t)RELS * NCHUNK * NB * 4;
    unsigned* bbR   = (unsigned*)q;               q += (size_t)RELS * (NB + 1) * 4;
    unsigned* bbC   = (unsigned*)q;
    unsigned short* aggbf = (unsigned short*)BIG;
    unsigned short* H2bf  = (unsigned short*)(BIG + AGGS);

    // CSR build: bucket radix sort (zero global atomics, no memsets)
    {
        dim3 hg(NCHUNK, RELS);
        dim3 bg(NB, RELS);
        k_bhist<<<hg, 256, 0, stream>>>(edges, 0, partR);
        k_bhist<<<hg, 256, 0, stream>>>(edges, EDGES, partC);
        k_bscan<<<RELS, 256, 0, stream>>>(partR, offR, bbR);
        k_bscan<<<RELS, 256, 0, stream>>>(partC, offC, bbC);
        k_scatR<<<hg, 256, 0, stream>>>(edges, offR, ebuf);
        k_scatC<<<hg, 256, 0, stream>>>(edges, offC, cbuf);
        k_countR<<<bg, 256, 0, stream>>>(ebuf, bbR, deg_row);
        k_countC<<<bg, 256, 0, stream>>>(cbuf, bbC, deg_col);
        k_dinv<<<cdiv(RELS * NODES, 256), 256, 0, stream>>>(deg_row, deg_col, dinv_row, dinv_col);
        dim3 sg(NSBLK, RELS);
        k_scanA<<<sg, 256, 0, stream>>>(deg_row, tmp, btot);
        k_scanB<<<RELS, 64, 0, stream>>>(btot, row_ptr);
        k_scanC<<<sg, 256, 0, stream>>>(tmp, btot, row_ptr);
        k_place<<<bg, 256, 0, stream>>>(ebuf, bbR, row_ptr, csr_col);
    }

    // conversions
    k_f2bf<<<cdiv(NODES * FEAT, 256), 256, 0, stream>>>(X, Xbf, NODES * FEAT);
    k_wt<<<cdiv(RELS * FEAT * FEAT, 256), 256, 0, stream>>>(W1, W1t);
    k_wt<<<cdiv(RELS * FEAT * FEAT, 256), 256, 0, stream>>>(W2, W2t);

    dim3 gemm_grid(MPAD / 128, FEAT / 128);

    // Layer 1: 4 SPMMs into 4 agg slices, then one fused GEMM -> h1bf
    for (int r = 0; r < RELS; ++r)
        k_spmm<<<cdiv(NODES * 64, 256), 256, 0, stream>>>(Xbf, row_ptr, csr_col,
                                                          dinv_row, dinv_col,
                                                          aggbf + (size_t)r * MPAD * FEAT, r);
    k_gemm1<<<gemm_grid, 256, 0, stream>>>(aggbf, W1t, h1bf);

    // Layer 2: per relation, SPMM into slice 0 then GEMM -> H2bf[r]
    for (int r = 0; r < RELS; ++r) {
        k_spmm<<<cdiv(NODES * 64, 256), 256, 0, stream>>>(h1bf, row_ptr, csr_col,
                                                          dinv_row, dinv_col, aggbf, r);
        k_gemm2<<<gemm_grid, 256, 0, stream>>>(aggbf, W2t + (size_t)r * FEAT * FEAT,
                                               H2bf + (size_t)r * NODES * FEAT);
    }

    // fused attention + output (single pass over H2bf)
    k_attn_out<<<1024, 256, 0, stream>>>(H2bf, att_q, tau, W_out, b_out, alpha, logits);
}